// Round 1
// baseline (579.487 us; speedup 1.0000x reference)
//
#include <hip/hip_runtime.h>
#include <hip/hip_bf16.h>
#include <stdint.h>

// Problem constants: B=32, S=1024, D=1024, 14 diseases x 2 states.
// M = B*S = 32768 rows. Gate GEMM: [z|R] (32768x2048) x gate_w^T (2048x1024).

typedef __attribute__((ext_vector_type(8))) short bf16x8;   // 4 VGPRs, MFMA A/B frag
typedef __attribute__((ext_vector_type(4))) float f32x4;    // MFMA C/D frag

__device__ __forceinline__ unsigned short f2bf(float f) {   // RNE fp32->bf16
  unsigned x = __float_as_uint(f);
  return (unsigned short)((x + 0x7FFFu + ((x >> 16) & 1u)) >> 16);
}
__device__ __forceinline__ float bf2f(unsigned short u) {
  return __uint_as_float(((unsigned)u) << 16);
}

typedef const __attribute__((address_space(1))) uint32_t* gptr_t;
typedef __attribute__((address_space(3))) uint32_t* lptr_t;
__device__ __forceinline__ void gload16(const void* g, void* l) {
  // async global->LDS, 16B per lane; LDS dest = wave-uniform base + lane*16
  __builtin_amdgcn_global_load_lds((gptr_t)g, (lptr_t)l, 16, 0, 0);
}

// ---------------- K0: convert gate_w (1024x2048) and flat_memory (28x1024, pad to 32) to bf16
__global__ __launch_bounds__(256) void k_convert_wfm(const float* __restrict__ w,
                                                     const float* __restrict__ dk,
                                                     ushort* __restrict__ wb,
                                                     ushort* __restrict__ fmb) {
  int i = blockIdx.x * 256 + threadIdx.x;
  if (i < 524288) {                       // 2097152/4 float4s of gate_w
    float4 v = ((const float4*)w)[i];
    uint2 o;
    o.x = (unsigned)f2bf(v.x) | ((unsigned)f2bf(v.y) << 16);
    o.y = (unsigned)f2bf(v.z) | ((unsigned)f2bf(v.w) << 16);
    ((uint2*)wb)[i] = o;
  } else if (i < 524288 + 8192) {         // 32*1024/4 float4s of padded fm
    int j = i - 524288;
    float4 v = make_float4(0.f, 0.f, 0.f, 0.f);
    if (j < 7168) v = ((const float4*)dk)[j];   // 28*256 real float4s, rows 28..31 zero
    uint2 o;
    o.x = (unsigned)f2bf(v.x) | ((unsigned)f2bf(v.y) << 16);
    o.y = (unsigned)f2bf(v.z) | ((unsigned)f2bf(v.w) << 16);
    ((uint2*)fmb)[j] = o;
  }
}

// ---------------- K1: convert z (32768x1024 f32) to bf16
__global__ __launch_bounds__(256) void k_convert_z(const float* __restrict__ z,
                                                   ushort* __restrict__ zb) {
  int i = blockIdx.x * 256 + threadIdx.x;  // 4,194,304 threads x 8 elements
  const float4* z4 = (const float4*)z;
  float4 a = z4[2 * i], b = z4[2 * i + 1];
  uint4 o;
  o.x = (unsigned)f2bf(a.x) | ((unsigned)f2bf(a.y) << 16);
  o.y = (unsigned)f2bf(a.z) | ((unsigned)f2bf(a.w) << 16);
  o.z = (unsigned)f2bf(b.x) | ((unsigned)f2bf(b.y) << 16);
  o.w = (unsigned)f2bf(b.z) | ((unsigned)f2bf(b.w) << 16);
  ((uint4*)zb)[i] = o;
}

// ---------------- K2: score GEMM (M=32768, N=28 pad 32, K=1024) + pair softmax
//                 + probs[32768][14] + atomicMax mlc_probs[32][14]
// One wave per 16 rows; frags loaded straight from global (fm is 64KB -> L1/L2 resident).
__global__ __launch_bounds__(256) void k_score(const ushort* __restrict__ zb,
                                               const ushort* __restrict__ fmb,
                                               float* __restrict__ probs,
                                               float* __restrict__ mlc) {
  int tid = threadIdx.x, lane = tid & 63, wv = tid >> 6;
  int row0 = blockIdx.x * 64 + wv * 16;
  int fr = lane & 15, kb = (lane >> 4) << 3;    // A/B frag: row=lane&15, k=(lane>>4)*8+j
  const bf16x8* Az = (const bf16x8*)(zb + (size_t)(row0 + fr) * 1024 + kb);
  const bf16x8* B0 = (const bf16x8*)(fmb + (size_t)fr * 1024 + kb);
  const bf16x8* B1 = (const bf16x8*)(fmb + (size_t)(16 + fr) * 1024 + kb);
  f32x4 acc0 = {0.f, 0.f, 0.f, 0.f}, acc1 = {0.f, 0.f, 0.f, 0.f};
  for (int k0 = 0; k0 < 1024; k0 += 32) {
    bf16x8 a  = Az[k0 >> 3];
    bf16x8 b0 = B0[k0 >> 3];
    bf16x8 b1 = B1[k0 >> 3];
    acc0 = __builtin_amdgcn_mfma_f32_16x16x32_bf16(a, b0, acc0, 0, 0, 0);
    acc1 = __builtin_amdgcn_mfma_f32_16x16x32_bf16(a, b1, acc1, 0, 0, 0);
  }
  // C/D layout: col = lane&15 (memory-row index m), row = (lane>>4)*4+reg  [m89]
  const float inv32 = 1.0f / 32.0f;   // score scale 1/sqrt(1024)
  int rsub = (lane >> 4) << 2;
  int bidx = row0 >> 10;              // batch index (blocks never straddle b)
  for (int f = 0; f < 2; ++f) {
    f32x4 s = f ? acc1 : acc0;
    float part[4];
#pragma unroll
    for (int rg = 0; rg < 4; ++rg) part[rg] = __shfl_xor(s[rg], 1);  // partner state
    int jj = f * 16 + fr;
    if ((lane & 1) && jj < 28) {      // odd lanes hold state-1 scores
      int dis = (jj - 1) >> 1;
      float pmax = 0.f;
#pragma unroll
      for (int rg = 0; rg < 4; ++rg) {
        // p1 = sigmoid((s1-s0)/32); own=s1, partner=s0
        float p = 1.f / (1.f + __expf((part[rg] - s[rg]) * inv32));
        probs[(size_t)(row0 + rsub + rg) * 14 + dis] = p;
        pmax = fmaxf(pmax, p);
      }
      // probs>0, mlc zero-initialized -> uint bit-pattern max == float max
      atomicMax((unsigned int*)&mlc[bidx * 14 + dis], __float_as_uint(pmax));
    }
  }
}

// ---------------- K3: R[row][d] = sum_i probs[row][i] * M_present[i][d], store bf16
__global__ __launch_bounds__(256) void k_R(const float* __restrict__ probs,
                                           const float* __restrict__ dk,
                                           ushort* __restrict__ Rb) {
  int t = threadIdx.x;
  int d0 = t << 2;                 // 256 threads cover 1024 dims, 4 each
  int row0 = blockIdx.x << 7;      // 128 rows per block
  float4 M[14];
#pragma unroll
  for (int i = 0; i < 14; ++i)
    M[i] = *(const float4*)&dk[(size_t)(i * 2 + 1) * 1024 + d0];  // state-1 rows
  for (int r = 0; r < 128; ++r) {
    int row = row0 + r;
    const float* pr = probs + (size_t)row * 14;
    float4 a = make_float4(0.f, 0.f, 0.f, 0.f);
#pragma unroll
    for (int i = 0; i < 14; ++i) {
      float p = pr[i];
      a.x = fmaf(p, M[i].x, a.x); a.y = fmaf(p, M[i].y, a.y);
      a.z = fmaf(p, M[i].z, a.z); a.w = fmaf(p, M[i].w, a.w);
    }
    uint2 o;
    o.x = (unsigned)f2bf(a.x) | ((unsigned)f2bf(a.y) << 16);
    o.y = (unsigned)f2bf(a.z) | ((unsigned)f2bf(a.w) << 16);
    *(uint2*)(Rb + (size_t)row * 1024 + d0) = o;
  }
}

// ---------------- K4: gate GEMM, m97 structure: 128x128 tile, BK=32, 4 waves (2x2),
// global_load_lds width 16, fused sigmoid-gate epilogue.
// C[r][d] = sum_k [z|R]bf16[r][k] * w_bf16[d][k];  out = z + sigmoid(C + b[d]) * R
__global__ __launch_bounds__(256) void k_gate(const ushort* __restrict__ zb,
                                              const ushort* __restrict__ Rb,
                                              const ushort* __restrict__ wb,
                                              const float* __restrict__ z,
                                              const float* __restrict__ gb,
                                              float* __restrict__ out) {
  __shared__ ushort Als[128 * 32];  // 8KB, linear row-major [128][32]
  __shared__ ushort Bls[128 * 32];  // 8KB
  int tid = threadIdx.x;
  // bijective XCD swizzle (2048 % 8 == 0): contiguous row-panels per XCD
  int nwg = gridDim.x;
  int swz = (blockIdx.x & 7) * (nwg >> 3) + (blockIdx.x >> 3);
  int row0 = (swz >> 3) << 7;      // 256 row-blocks
  int col0 = (swz & 7) << 7;       // 8 col-blocks
  int lane = tid & 63, wid = tid >> 6;
  int wr = wid >> 1, wc = wid & 1; // 2x2 wave grid, each wave 64x64 out
  int sr = tid >> 2;               // staging: row 0..63 of tile
  int sc = (tid & 3) << 3;         // staging: elem col 0,8,16,24
  int fr = lane & 15, kb = (lane >> 4) << 3;
  f32x4 acc[4][4] = {};
  char* Ad = ((char*)Als) + wid * 1024;
  char* Bd = ((char*)Bls) + wid * 1024;
  for (int k0 = 0; k0 < 2048; k0 += 32) {
    const ushort* Asrc = (k0 < 1024)
        ? (zb + (size_t)(row0 + sr) * 1024 + (k0 + sc))
        : (Rb + (size_t)(row0 + sr) * 1024 + (k0 - 1024 + sc));
    const ushort* Bsrc = wb + (size_t)(col0 + sr) * 2048 + (k0 + sc);
    gload16(Asrc, Ad);
    gload16(Asrc + (size_t)64 * 1024, Ad + 4096);
    gload16(Bsrc, Bd);
    gload16(Bsrc + (size_t)64 * 2048, Bd + 4096);
    __syncthreads();
    bf16x8 af[4], bf_[4];
#pragma unroll
    for (int ai = 0; ai < 4; ++ai)
      af[ai] = *(const bf16x8*)&Als[(wr * 64 + ai * 16 + fr) * 32 + kb];
#pragma unroll
    for (int bj = 0; bj < 4; ++bj)
      bf_[bj] = *(const bf16x8*)&Bls[(wc * 64 + bj * 16 + fr) * 32 + kb];
#pragma unroll
    for (int ai = 0; ai < 4; ++ai)
#pragma unroll
      for (int bj = 0; bj < 4; ++bj)
        acc[ai][bj] = __builtin_amdgcn_mfma_f32_16x16x32_bf16(af[ai], bf_[bj], acc[ai][bj], 0, 0, 0);
    __syncthreads();
  }
  // epilogue: gate = sigmoid(acc + gb[c]); out = z + gate*R
  int rsub = (lane >> 4) << 2;
#pragma unroll
  for (int ai = 0; ai < 4; ++ai) {
#pragma unroll
    for (int bj = 0; bj < 4; ++bj) {
      int c = col0 + wc * 64 + bj * 16 + fr;
      float gbias = gb[c];
      f32x4 a = acc[ai][bj];
#pragma unroll
      for (int rg = 0; rg < 4; ++rg) {
        int r = row0 + wr * 64 + ai * 16 + rsub + rg;
        size_t o = (size_t)r * 1024 + c;
        float g = 1.f / (1.f + __expf(-(a[rg] + gbias)));
        out[o] = fmaf(g, bf2f(Rb[o]), z[o]);
      }
    }
  }
}

extern "C" void kernel_launch(void* const* d_in, const int* in_sizes, int n_in,
                              void* d_out, int out_size, void* d_ws, size_t ws_size,
                              hipStream_t stream) {
  const float* z  = (const float*)d_in[0];   // (32,1024,1024)
  const float* dk = (const float*)d_in[1];   // (14,2,1024)
  const float* gw = (const float*)d_in[2];   // (1024,2048)
  const float* gb = (const float*)d_in[3];   // (1024,)
  float* out = (float*)d_out;                // z_out (33554432) ++ mlc (448)

  char* ws = (char*)d_ws;                    // ~134 MB used
  ushort* zb   = (ushort*)(ws);                    // 64 MB  bf16 z
  ushort* Rb   = (ushort*)(ws + 67108864);         // 64 MB  bf16 R
  ushort* wb   = (ushort*)(ws + 134217728);        // 4 MB   bf16 gate_w
  ushort* fmb  = (ushort*)(ws + 138412032);        // 64 KB  bf16 fm padded [32][1024]
  float*  probs= (float*)(ws + 138477568);         // 1.75MB probs [32768][14]
  float*  mlc  = out + 33554432;

  hipMemsetAsync(mlc, 0, 448 * sizeof(float), stream);   // atomicMax identity
  k_convert_wfm<<<2080, 256, 0, stream>>>(gw, dk, wb, fmb);
  k_convert_z<<<16384, 256, 0, stream>>>(z, zb);
  k_score<<<512, 256, 0, stream>>>(zb, fmb, probs, mlc);
  k_R<<<256, 256, 0, stream>>>(probs, dk, Rb);
  k_gate<<<2048, 256, 0, stream>>>(zb, Rb, wb, z, gb, out);
}

// Round 2
// 515.070 us; speedup vs baseline: 1.1251x; 1.1251x over previous
//
#include <hip/hip_runtime.h>
#include <hip/hip_bf16.h>
#include <stdint.h>

// B=32, S=1024, D=1024, 14 diseases x 2 states. M = 32768 rows.
// Gate GEMM: [z|R] (32768x2048) x gate_w^T (2048x1024).

typedef __attribute__((ext_vector_type(8))) short bf16x8;   // MFMA A/B frag
typedef __attribute__((ext_vector_type(4))) float f32x4;    // MFMA C/D frag

__device__ __forceinline__ unsigned short f2bf(float f) {   // RNE fp32->bf16
  unsigned x = __float_as_uint(f);
  return (unsigned short)((x + 0x7FFFu + ((x >> 16) & 1u)) >> 16);
}
__device__ __forceinline__ unsigned pk2(float a, float b) {
  return (unsigned)f2bf(a) | ((unsigned)f2bf(b) << 16);
}
__device__ __forceinline__ float bf2f(unsigned short u) {
  return __uint_as_float(((unsigned)u) << 16);
}

typedef const __attribute__((address_space(1))) uint32_t* gptr_t;
typedef __attribute__((address_space(3))) uint32_t* lptr_t;
__device__ __forceinline__ void gload16(const void* g, void* l) {
  __builtin_amdgcn_global_load_lds((gptr_t)g, (lptr_t)l, 16, 0, 0);
}

// ---------------- K0: convert gate_w (1024x2048) + flat_memory (28x1024 pad 32) to bf16
__global__ __launch_bounds__(256) void k_convert_wfm(const float* __restrict__ w,
                                                     const float* __restrict__ dk,
                                                     ushort* __restrict__ wb,
                                                     ushort* __restrict__ fmb) {
  int i = blockIdx.x * 256 + threadIdx.x;
  if (i < 524288) {                       // gate_w float4s
    float4 v = ((const float4*)w)[i];
    uint2 o; o.x = pk2(v.x, v.y); o.y = pk2(v.z, v.w);
    ((uint2*)wb)[i] = o;
  } else if (i < 524288 + 8192) {         // padded fm float4s
    int j = i - 524288;
    float4 v = make_float4(0.f, 0.f, 0.f, 0.f);
    if (j < 7168) v = ((const float4*)dk)[j];
    uint2 o; o.x = pk2(v.x, v.y); o.y = pk2(v.z, v.w);
    ((uint2*)fmb)[j] = o;
  }
}

// ---------------- K1 (fused): convert z->zb, score MFMA, pair-softmax, mlc max, R->Rb.
// 512 blocks x 256 threads (4 waves); 64 rows per block. z read once, coalesced.
__global__ __launch_bounds__(256) void k_fused(const float* __restrict__ z,
                                               const ushort* __restrict__ fmb,
                                               const float* __restrict__ dk,
                                               ushort* __restrict__ zb,
                                               ushort* __restrict__ Rb,
                                               float* __restrict__ mlc) {
  __shared__ ushort At[64][72];   // 64 rows x 64 k-chunk, +8 pad (2-way banks on b128)
  __shared__ float pbuf[64][16];  // per-row disease probs
  int tid = threadIdx.x, lane = tid & 63, wv = tid >> 6;
  int row0 = blockIdx.x * 64;
  int srow = tid >> 2;            // staging row 0..63
  int scol = (tid & 3) << 4;      // staging col 0,16,32,48 (bf16 elems)
  int fr = lane & 15, kb = (lane >> 4) << 3;
  const bf16x8* B0 = (const bf16x8*)(fmb + (size_t)fr * 1024 + kb);        // fm rows 0-15
  const bf16x8* B1 = (const bf16x8*)(fmb + (size_t)(16 + fr) * 1024 + kb); // fm rows 16-31
  f32x4 acc0 = {0.f, 0.f, 0.f, 0.f}, acc1 = {0.f, 0.f, 0.f, 0.f};
  const float4* zsrc = (const float4*)&z[(size_t)(row0 + srow) * 1024];
  uint4* zdst = (uint4*)&zb[(size_t)(row0 + srow) * 1024];
  for (int kc = 0; kc < 1024; kc += 64) {
    int e0 = (kc + scol) >> 2;    // float4 index into row
    float4 v0 = zsrc[e0], v1 = zsrc[e0 + 1], v2 = zsrc[e0 + 2], v3 = zsrc[e0 + 3];
    uint4 o0, o1;
    o0.x = pk2(v0.x, v0.y); o0.y = pk2(v0.z, v0.w);
    o0.z = pk2(v1.x, v1.y); o0.w = pk2(v1.z, v1.w);
    o1.x = pk2(v2.x, v2.y); o1.y = pk2(v2.z, v2.w);
    o1.z = pk2(v3.x, v3.y); o1.w = pk2(v3.z, v3.w);
    int eo = (kc + scol) >> 3;    // uint4 (8 bf16) index into row
    zdst[eo] = o0; zdst[eo + 1] = o1;
    *(uint4*)&At[srow][scol] = o0;
    *(uint4*)&At[srow][scol + 8] = o1;
    __syncthreads();
#pragma unroll
    for (int kk = 0; kk < 64; kk += 32) {
      bf16x8 a = *(const bf16x8*)&At[wv * 16 + fr][kk + kb];
      bf16x8 b0 = B0[(kc + kk) >> 3];
      bf16x8 b1 = B1[(kc + kk) >> 3];
      acc0 = __builtin_amdgcn_mfma_f32_16x16x32_bf16(a, b0, acc0, 0, 0, 0);
      acc1 = __builtin_amdgcn_mfma_f32_16x16x32_bf16(a, b1, acc1, 0, 0, 0);
    }
    __syncthreads();
  }
  // pair softmax: p1 = sigmoid((s1-s0)/32); write to pbuf + atomicMax into mlc
  const float inv32 = 1.0f / 32.0f;
  int rsub = (lane >> 4) << 2;
  int bidx = row0 >> 10;          // batch index (64 | 1024, never straddles)
#pragma unroll
  for (int f = 0; f < 2; ++f) {
    f32x4 s = f ? acc1 : acc0;
    float part[4];
#pragma unroll
    for (int rg = 0; rg < 4; ++rg) part[rg] = __shfl_xor(s[rg], 1);
    int jj = f * 16 + fr;
    if ((lane & 1) && jj < 28) {
      int dis = (jj - 1) >> 1;
      float pmax = 0.f;
#pragma unroll
      for (int rg = 0; rg < 4; ++rg) {
        float p = 1.f / (1.f + __expf((part[rg] - s[rg]) * inv32));
        pbuf[wv * 16 + rsub + rg][dis] = p;
        pmax = fmaxf(pmax, p);
      }
      atomicMax((unsigned int*)&mlc[bidx * 14 + dis], __float_as_uint(pmax));
    }
  }
  __syncthreads();
  // R phase: R[row][d] = sum_i p[row][i] * M_present[i][d]; 4 dims per thread
  int d0 = tid << 2;
  float4 M[14];
#pragma unroll
  for (int i = 0; i < 14; ++i)
    M[i] = *(const float4*)&dk[(size_t)(i * 2 + 1) * 1024 + d0];
  for (int r = 0; r < 64; ++r) {
    const float* pr = pbuf[r];
    float4 a = make_float4(0.f, 0.f, 0.f, 0.f);
#pragma unroll
    for (int i = 0; i < 14; ++i) {
      float p = pr[i];
      a.x = fmaf(p, M[i].x, a.x); a.y = fmaf(p, M[i].y, a.y);
      a.z = fmaf(p, M[i].z, a.z); a.w = fmaf(p, M[i].w, a.w);
    }
    uint2 o; o.x = pk2(a.x, a.y); o.y = pk2(a.z, a.w);
    *(uint2*)&Rb[(size_t)(row0 + r) * 1024 + d0] = o;
  }
}

// ---------------- K2: gate GEMM, 128x128 tile, BK=32, 4 waves (2x2), DOUBLE-BUFFERED
// LDS (T3 minimum recipe: stage next -> compute current -> one barrier/iter).
// out = zb + sigmoid(C + b[d]) * Rb   (bf16 z in epilogue: -64MB HBM)
__global__ __launch_bounds__(256) void k_gate(const ushort* __restrict__ zb,
                                              const ushort* __restrict__ Rb,
                                              const ushort* __restrict__ wb,
                                              const float* __restrict__ gb,
                                              float* __restrict__ out) {
  __shared__ ushort Als[2][128 * 32];  // 2 x 8KB
  __shared__ ushort Bls[2][128 * 32];
  int tid = threadIdx.x;
  int nwg = gridDim.x;  // 2048, %8==0 -> bijective XCD swizzle
  int swz = (blockIdx.x & 7) * (nwg >> 3) + (blockIdx.x >> 3);
  int row0 = (swz >> 3) << 7;
  int col0 = (swz & 7) << 7;
  int lane = tid & 63, wid = tid >> 6;
  int wr = wid >> 1, wc = wid & 1;
  int sr = tid >> 2, sc = (tid & 3) << 3;
  int fr = lane & 15, kb = (lane >> 4) << 3;
  f32x4 acc[4][4] = {};

  auto stage = [&](int k0, int buf) {
    const ushort* Asrc = (k0 < 1024)
        ? (zb + (size_t)(row0 + sr) * 1024 + (k0 + sc))
        : (Rb + (size_t)(row0 + sr) * 1024 + (k0 - 1024 + sc));
    const ushort* Bsrc = wb + (size_t)(col0 + sr) * 2048 + (k0 + sc);
    char* Ad = ((char*)&Als[buf][0]) + wid * 1024;
    char* Bd = ((char*)&Bls[buf][0]) + wid * 1024;
    gload16(Asrc, Ad);
    gload16(Asrc + (size_t)64 * 1024, Ad + 4096);
    gload16(Bsrc, Bd);
    gload16(Bsrc + (size_t)64 * 2048, Bd + 4096);
  };

  stage(0, 0);
  __syncthreads();                 // drains vmcnt(0): buf0 ready
  int cur = 0;
  for (int k0 = 32; k0 <= 2048; k0 += 32) {
    if (k0 < 2048) stage(k0, cur ^ 1);   // prefetch stays in flight during compute
    bf16x8 af[4], bfr[4];
#pragma unroll
    for (int ai = 0; ai < 4; ++ai)
      af[ai] = *(const bf16x8*)&Als[cur][(wr * 64 + ai * 16 + fr) * 32 + kb];
#pragma unroll
    for (int bj = 0; bj < 4; ++bj)
      bfr[bj] = *(const bf16x8*)&Bls[cur][(wc * 64 + bj * 16 + fr) * 32 + kb];
#pragma unroll
    for (int ai = 0; ai < 4; ++ai)
#pragma unroll
      for (int bj = 0; bj < 4; ++bj)
        acc[ai][bj] = __builtin_amdgcn_mfma_f32_16x16x32_bf16(af[ai], bfr[bj], acc[ai][bj], 0, 0, 0);
    __syncthreads();               // single barrier: drains prefetch + LDS reuse safe
    cur ^= 1;
  }
  // epilogue: gate = sigmoid(acc + gb[c]); out = z + gate*R (z, R from bf16)
  int rsub = (lane >> 4) << 2;
#pragma unroll
  for (int ai = 0; ai < 4; ++ai) {
#pragma unroll
    for (int bj = 0; bj < 4; ++bj) {
      int c = col0 + wc * 64 + bj * 16 + fr;
      float gbias = gb[c];
      f32x4 a = acc[ai][bj];
#pragma unroll
      for (int rg = 0; rg < 4; ++rg) {
        int r = row0 + wr * 64 + ai * 16 + rsub + rg;
        size_t o = (size_t)r * 1024 + c;
        float g = 1.f / (1.f + __expf(-(a[rg] + gbias)));
        out[o] = fmaf(g, bf2f(Rb[o]), bf2f(zb[o]));
      }
    }
  }
}

extern "C" void kernel_launch(void* const* d_in, const int* in_sizes, int n_in,
                              void* d_out, int out_size, void* d_ws, size_t ws_size,
                              hipStream_t stream) {
  const float* z  = (const float*)d_in[0];   // (32,1024,1024)
  const float* dk = (const float*)d_in[1];   // (14,2,1024)
  const float* gw = (const float*)d_in[2];   // (1024,2048)
  const float* gb = (const float*)d_in[3];   // (1024,)
  float* out = (float*)d_out;                // z_out (33554432) ++ mlc (448)

  char* ws = (char*)d_ws;
  ushort* zb  = (ushort*)(ws);               // 64 MB bf16 z
  ushort* Rb  = (ushort*)(ws + 67108864);    // 64 MB bf16 R
  ushort* wb  = (ushort*)(ws + 134217728);   // 4 MB  bf16 gate_w
  ushort* fmb = (ushort*)(ws + 138412032);   // 64 KB bf16 fm padded [32][1024]
  float*  mlc = out + 33554432;

  hipMemsetAsync(mlc, 0, 448 * sizeof(float), stream);   // atomicMax identity
  k_convert_wfm<<<2080, 256, 0, stream>>>(gw, dk, wb, fmb);
  k_fused<<<512, 256, 0, stream>>>(z, fmb, dk, zb, Rb, mlc);
  k_gate<<<2048, 256, 0, stream>>>(zb, Rb, wb, gb, out);
}